// Round 5
// baseline (134.070 us; speedup 1.0000x reference)
//
#include <hip/hip_runtime.h>
#include <hip/hip_bf16.h>

typedef unsigned short u16;
typedef unsigned int u32;
typedef __attribute__((ext_vector_type(8))) short bf16x8;
typedef __attribute__((ext_vector_type(4))) float f32x4;
typedef __attribute__((ext_vector_type(2))) float f32x2;
typedef __attribute__((ext_vector_type(4))) unsigned short u16x4;

#define T_TILES 4   // 64-row tiles per block (pipelined)

// shared_exp = floor(log2(amax)) - 8 ; scale = 2^shared_exp (power of two)
__device__ __forceinline__ void block_scale(float amax, float& scale, float& inv_scale) {
    int be = (int)(__float_as_uint(amax) >> 23);   // biased exponent, amax >= 0
    be = be < 8 ? 8 : be;                          // tiny/zero blocks quantize to 0 anyway
    scale     = __uint_as_float((unsigned)(be - 8) << 23);   // 2^(be-135)
    inv_scale = __uint_as_float((unsigned)(262 - be) << 23); // 2^(135-be)
}

#if __has_builtin(__builtin_amdgcn_cvt_pk_fp8_f32) && __has_builtin(__builtin_amdgcn_cvt_pk_f32_fp8)
#define HAS_HW_FP8 1
#else
#define HAS_HW_FP8 0
#endif

#if !HAS_HW_FP8
// Fallback: exact bit-math e4m3 RNE (verified in round 0)
__device__ __forceinline__ float mx_e4m3(float x, float inv_scale, float scale) {
    float v  = x * inv_scale;
    float av = fabsf(v);
    int e = (int)(__float_as_uint(av) >> 23) - 127;
    e = e < -6 ? -6 : (e > 8 ? 8 : e);
    float qs = __uint_as_float((unsigned)(130 - e) << 23);
    float qm = __uint_as_float((unsigned)(124 + e) << 23);
    float q  = fminf(rintf(av * qs) * qm, 448.0f);
    return copysignf(q, v) * scale;
}
#endif

// Quantize 4 elems to e4m3 grid (RNE, saturate 448), return bf16 bits of value*scale.
// bf16 conversion is exact (e4m3: 4 significand bits; bf16: 8).
__device__ __forceinline__ u16x4 quant4(float4 v, float inv, float sc) {
    u16x4 r;
#if HAS_HW_FP8
    // pre-clamp to +-448: v can reach 511 (amax in upper half of its binade); ref saturates at 448
    float a = fminf(fmaxf(v.x * inv, -448.f), 448.f);
    float b = fminf(fmaxf(v.y * inv, -448.f), 448.f);
    float c = fminf(fmaxf(v.z * inv, -448.f), 448.f);
    float d = fminf(fmaxf(v.w * inv, -448.f), 448.f);
    int p = __builtin_amdgcn_cvt_pk_fp8_f32(a, b, 0, false);   // RNE f32->e4m3 (OCP on gfx950)
    p     = __builtin_amdgcn_cvt_pk_fp8_f32(c, d, p, true);
    f32x2 lo = __builtin_amdgcn_cvt_pk_f32_fp8(p, false);      // exact e4m3->f32
    f32x2 hi = __builtin_amdgcn_cvt_pk_f32_fp8(p, true);
    r.x = (u16)(__float_as_uint(lo[0] * sc) >> 16);
    r.y = (u16)(__float_as_uint(lo[1] * sc) >> 16);
    r.z = (u16)(__float_as_uint(hi[0] * sc) >> 16);
    r.w = (u16)(__float_as_uint(hi[1] * sc) >> 16);
#else
    r.x = (u16)(__float_as_uint(mx_e4m3(v.x, inv, sc)) >> 16);
    r.y = (u16)(__float_as_uint(mx_e4m3(v.y, inv, sc)) >> 16);
    r.z = (u16)(__float_as_uint(mx_e4m3(v.z, inv, sc)) >> 16);
    r.w = (u16)(__float_as_uint(mx_e4m3(v.w, inv, sc)) >> 16);
#endif
    return r;
}

// Quantize 256x256 weight to bf16 fake-quant, stored TRANSPOSED: Bq[n*256+k].
// MX blocks are 32 consecutive n at fixed k (flat reshape of row-major (K,N)).
__global__ void wq_kernel(const float* __restrict__ W, u16* __restrict__ Bq) {
    const int t  = blockIdx.x * blockDim.x + threadIdx.x;
    const int f  = t * 4;
    const int k  = f >> 8;
    const int n0 = f & 255;
    const float4 v = *(const float4*)(W + f);
    float am = fmaxf(fmaxf(fabsf(v.x), fabsf(v.y)), fmaxf(fabsf(v.z), fabsf(v.w)));
    am = fmaxf(am, __shfl_xor(am, 1));   // 8 lanes x 4 elems = one 32-elem MX block
    am = fmaxf(am, __shfl_xor(am, 2));
    am = fmaxf(am, __shfl_xor(am, 4));
    float sc, inv; block_scale(am, sc, inv);
    u16x4 q = quant4(v, inv, sc);
    Bq[(size_t)(n0 + 0) * 256 + k] = q.x;
    Bq[(size_t)(n0 + 1) * 256 + k] = q.y;
    Bq[(size_t)(n0 + 2) * 256 + k] = q.z;
    Bq[(size_t)(n0 + 3) * 256 + k] = q.w;
}

// Quantize 16 rows (this wave's slice) of xv into swizzled bf16 LDS buffer.
__device__ __forceinline__ void quant_tile(const float4* xv, u16* Abuf,
                                           int w, int l) {
    #pragma unroll
    for (int it = 0; it < 16; ++it) {
        const int r = w * 16 + it;
        float4 v = xv[it];
        float am = fmaxf(fmaxf(fabsf(v.x), fabsf(v.y)), fmaxf(fabsf(v.z), fabsf(v.w)));
        am = fmaxf(am, __shfl_xor(am, 1));  // 8-lane group = one 32-elem MX block (along K)
        am = fmaxf(am, __shfl_xor(am, 2));
        am = fmaxf(am, __shfl_xor(am, 4));
        float sc, inv; block_scale(am, sc, inv);
        u16x4 q = quant4(v, inv, sc);
        // all lanes same row -> uniform XOR, contiguous 512B, conflict-free
        char* dst = (char*)Abuf + (((u32)(r * 512 + l * 8)) ^ ((u32)(r & 7) << 4));
        *(u16x4*)dst = q;
    }
}

// Pipelined GEMM: each block owns T_TILES consecutive 64-row tiles.
// Per iteration: issue next tile's 16 X-loads (stay in flight under compute),
// MFMA current tile from LDS (double-buffered), quantize next tile, 1 barrier.
__global__ void __launch_bounds__(256, 2)
mx_gemm(const float* __restrict__ X, const u16* __restrict__ Bq,
        const float* __restrict__ bias, float* __restrict__ out)
{
    __shared__ u16 A[2][64 * 256];       // 2 x 32 KB, XOR-swizzled
    const int tid = threadIdx.x;
    const int w   = tid >> 6;
    const int l   = tid & 63;
    const int lr  = l & 15;
    const int lg  = l >> 4;
    const size_t row00 = (size_t)blockIdx.x * (64 * T_TILES);

    const int kc = l * 4;
    const float* xw = X + (row00 + w * 16) * 256 + kc;   // wave's first row, lane's k
    float4 xv[16];

    // ---- prologue: load + quantize tile 0 ----
    #pragma unroll
    for (int it = 0; it < 16; ++it)
        xv[it] = *(const float4*)(xw + it * 256);
    __builtin_amdgcn_sched_barrier(0);
    quant_tile(xv, &A[0][0], w, l);
    __syncthreads();

    // hoisted per-wave constants
    const u16* bb = Bq + (size_t)(w * 64 + lr) * 256 + lg * 8;
    float4 bv[4];
    #pragma unroll
    for (int ct = 0; ct < 4; ++ct)
        bv[ct] = *(const float4*)(bias + w * 64 + ct * 16 + lg * 4);

    for (int t = 0; t < T_TILES; ++t) {
        // ---- issue next tile's X loads FIRST (16 x 1KB in flight per wave) ----
        if (t + 1 < T_TILES) {
            const float* xn = xw + (size_t)(t + 1) * 64 * 256;
            #pragma unroll
            for (int it = 0; it < 16; ++it)
                xv[it] = *(const float4*)(xn + it * 256);
        }
        __builtin_amdgcn_sched_barrier(0);   // pin: loads above, compute below

        // ---- MFMA tile t: A from LDS buf t&1, B from L2 (1-deep prefetch) ----
        const u16* Ab = &A[t & 1][0];
        f32x4 acc[4][4] = {};
        bf16x8 bcur[4], bnxt[4];
        #pragma unroll
        for (int ct = 0; ct < 4; ++ct)
            bcur[ct] = *(const bf16x8*)(bb + (size_t)ct * 16 * 256);
        #pragma unroll
        for (int ks = 0; ks < 8; ++ks) {
            bf16x8 af[4];
            #pragma unroll
            for (int rt = 0; rt < 4; ++rt) {
                const int row = rt * 16 + lr;
                const u32 off = ((u32)(row * 512 + ks * 64 + lg * 16)) ^ ((u32)(lr & 7) << 4);
                af[rt] = *(const bf16x8*)((const char*)Ab + off);
            }
            if (ks < 7) {
                #pragma unroll
                for (int ct = 0; ct < 4; ++ct)
                    bnxt[ct] = *(const bf16x8*)(bb + (size_t)ct * 16 * 256 + (ks + 1) * 32);
            }
            #pragma unroll
            for (int rt = 0; rt < 4; ++rt)
                #pragma unroll
                for (int ct = 0; ct < 4; ++ct)
                    acc[rt][ct] = __builtin_amdgcn_mfma_f32_16x16x32_bf16(
                        bcur[ct], af[rt], acc[rt][ct], 0, 0, 0);
            if (ks < 7) {
                #pragma unroll
                for (int ct = 0; ct < 4; ++ct) bcur[ct] = bnxt[ct];
            }
        }

        // ---- epilogue tile t: lane holds C[rt*16+lr][w*64+ct*16+lg*4 ..+3] ----
        const size_t row0 = row00 + (size_t)t * 64;
        #pragma unroll
        for (int ct = 0; ct < 4; ++ct)
            #pragma unroll
            for (int rt = 0; rt < 4; ++rt) {
                f32x4 o = acc[rt][ct];
                o[0] += bv[ct].x; o[1] += bv[ct].y; o[2] += bv[ct].z; o[3] += bv[ct].w;
                *(f32x4*)(out + (row0 + rt * 16 + lr) * 256 + w * 64 + ct * 16 + lg * 4) = o;
            }

        // ---- quantize tile t+1 into the other buffer ----
        if (t + 1 < T_TILES)
            quant_tile(xv, &A[(t + 1) & 1][0], w, l);
        __syncthreads();
    }
}

extern "C" void kernel_launch(void* const* d_in, const int* in_sizes, int n_in,
                              void* d_out, int out_size, void* d_ws, size_t ws_size,
                              hipStream_t stream) {
    const float* x    = (const float*)d_in[0];
    const float* wk   = (const float*)d_in[1];
    const float* bias = (const float*)d_in[2];
    float* out = (float*)d_out;
    u16* Bq    = (u16*)d_ws;                  // 256*256 bf16 = 128 KB scratch
    const int M = in_sizes[0] / 256;          // 131072 rows
    wq_kernel<<<64, 256, 0, stream>>>(wk, Bq);
    mx_gemm<<<M / (64 * T_TILES), 256, 0, stream>>>(x, Bq, bias, out);  // 512 blocks
}

// Round 6
// 90.993 us; speedup vs baseline: 1.4734x; 1.4734x over previous
//
#include <hip/hip_runtime.h>
#include <hip/hip_bf16.h>

typedef unsigned short u16;
typedef unsigned int u32;
typedef __attribute__((ext_vector_type(8))) short bf16x8;
typedef __attribute__((ext_vector_type(4))) float f32x4;
typedef __attribute__((ext_vector_type(2))) float f32x2;
typedef __attribute__((ext_vector_type(4))) unsigned short u16x4;

#define T_TILES 8    // 16-row tiles per block
#define NBLK    1024 // grid: 1024 * 8 * 16 = 131072 rows

// shared_exp = floor(log2(amax)) - 8 ; scale = 2^shared_exp (power of two)
__device__ __forceinline__ void block_scale(float amax, float& scale, float& inv_scale) {
    int be = (int)(__float_as_uint(amax) >> 23);   // biased exponent, amax >= 0
    be = be < 8 ? 8 : be;                          // tiny/zero blocks quantize to 0 anyway
    scale     = __uint_as_float((unsigned)(be - 8) << 23);   // 2^(be-135)
    inv_scale = __uint_as_float((unsigned)(262 - be) << 23); // 2^(135-be)
}

#if __has_builtin(__builtin_amdgcn_cvt_pk_fp8_f32) && __has_builtin(__builtin_amdgcn_cvt_pk_f32_fp8)
#define HAS_HW_FP8 1
#else
#define HAS_HW_FP8 0
#endif

#if !HAS_HW_FP8
// Fallback: exact bit-math e4m3 RNE (verified in round 0)
__device__ __forceinline__ float mx_e4m3(float x, float inv_scale, float scale) {
    float v  = x * inv_scale;
    float av = fabsf(v);
    int e = (int)(__float_as_uint(av) >> 23) - 127;
    e = e < -6 ? -6 : (e > 8 ? 8 : e);
    float qs = __uint_as_float((unsigned)(130 - e) << 23);
    float qm = __uint_as_float((unsigned)(124 + e) << 23);
    float q  = fminf(rintf(av * qs) * qm, 448.0f);
    return copysignf(q, v) * scale;
}
#endif

// Quantize 4 elems to e4m3 grid (RNE, saturate 448), return bf16 bits of value*scale.
// bf16 conversion is exact (e4m3: 4 significand bits; bf16: 8).
__device__ __forceinline__ u16x4 quant4(float4 v, float inv, float sc) {
    u16x4 r;
#if HAS_HW_FP8
    float a = fminf(fmaxf(v.x * inv, -448.f), 448.f);
    float b = fminf(fmaxf(v.y * inv, -448.f), 448.f);
    float c = fminf(fmaxf(v.z * inv, -448.f), 448.f);
    float d = fminf(fmaxf(v.w * inv, -448.f), 448.f);
    int p = __builtin_amdgcn_cvt_pk_fp8_f32(a, b, 0, false);   // RNE f32->e4m3 (OCP)
    p     = __builtin_amdgcn_cvt_pk_fp8_f32(c, d, p, true);
    f32x2 lo = __builtin_amdgcn_cvt_pk_f32_fp8(p, false);      // exact e4m3->f32
    f32x2 hi = __builtin_amdgcn_cvt_pk_f32_fp8(p, true);
    r.x = (u16)(__float_as_uint(lo[0] * sc) >> 16);
    r.y = (u16)(__float_as_uint(lo[1] * sc) >> 16);
    r.z = (u16)(__float_as_uint(hi[0] * sc) >> 16);
    r.w = (u16)(__float_as_uint(hi[1] * sc) >> 16);
#else
    r.x = (u16)(__float_as_uint(mx_e4m3(v.x, inv, sc)) >> 16);
    r.y = (u16)(__float_as_uint(mx_e4m3(v.y, inv, sc)) >> 16);
    r.z = (u16)(__float_as_uint(mx_e4m3(v.z, inv, sc)) >> 16);
    r.w = (u16)(__float_as_uint(mx_e4m3(v.w, inv, sc)) >> 16);
#endif
    return r;
}

// Quantize 256x256 weight to bf16 fake-quant, stored TRANSPOSED: Bq[n*256+k].
// MX blocks are 32 consecutive n at fixed k (flat reshape of row-major (K,N)).
__global__ void wq_kernel(const float* __restrict__ W, u16* __restrict__ Bq) {
    const int t  = blockIdx.x * blockDim.x + threadIdx.x;
    const int f  = t * 4;
    const int k  = f >> 8;
    const int n0 = f & 255;
    const float4 v = *(const float4*)(W + f);
    float am = fmaxf(fmaxf(fabsf(v.x), fabsf(v.y)), fmaxf(fabsf(v.z), fabsf(v.w)));
    am = fmaxf(am, __shfl_xor(am, 1));   // 8 lanes x 4 elems = one 32-elem MX block
    am = fmaxf(am, __shfl_xor(am, 2));
    am = fmaxf(am, __shfl_xor(am, 4));
    float sc, inv; block_scale(am, sc, inv);
    u16x4 q = quant4(v, inv, sc);
    Bq[(size_t)(n0 + 0) * 256 + k] = q.x;
    Bq[(size_t)(n0 + 1) * 256 + k] = q.y;
    Bq[(size_t)(n0 + 2) * 256 + k] = q.z;
    Bq[(size_t)(n0 + 3) * 256 + k] = q.w;
}

// Async-staged pipelined GEMM (T3 2-phase template):
//  - block = 4 waves; all waves share a 16-row f32 X tile in LDS (double-buffered,
//    filled by global_load_lds DMA -> zero VGPR staging cost, HBM stays fed).
//  - wave w owns cols [64w, 64w+64); its B slice lives in 128 VGPRs for the whole
//    kernel (loaded once from L2) -> the K-loop is reg-only MFMA, no vmcnt pollution.
//  - quantization reads f32 straight in fragment layout (lane: row lr, k=ks*32+lg*8),
//    amax via shfl_xor(16/32) across the 4 lg-lanes of a row (one 32-k MX block).
//  - LDS rows 16B-granule XOR-swizzled via PRE-SWIZZLED GLOBAL SOURCE (DMA writes
//    linearly); reads apply the same XOR -> uniform 2-lanes/bank (free).
__global__ void __launch_bounds__(256, 2)
mx_gemm(const float* __restrict__ X, const u16* __restrict__ Bq,
        const float* __restrict__ bias, float* __restrict__ out)
{
    __shared__ float Xs[2][16 * 256];    // 2 x 16 KB raw f32
    const int tid = threadIdx.x;
    const int w   = tid >> 6;
    const int l   = tid & 63;
    const int lr  = l & 15;
    const int lg  = l >> 4;
    const size_t row00 = (size_t)blockIdx.x * (16 * T_TILES);

    // ---- B slice -> registers (128 VGPRs), bias -> registers ----
    bf16x8 breg[4][8];
    {
        const u16* bb = Bq + (size_t)(w * 64 + lr) * 256 + lg * 8;
        #pragma unroll
        for (int ct = 0; ct < 4; ++ct)
            #pragma unroll
            for (int ks = 0; ks < 8; ++ks)
                breg[ct][ks] = *(const bf16x8*)(bb + (size_t)ct * 16 * 256 + ks * 32);
    }
    float4 bv[4];
    #pragma unroll
    for (int ct = 0; ct < 4; ++ct)
        bv[ct] = *(const float4*)(bias + w * 64 + ct * 16 + lg * 4);

    // ---- prologue: stage tile 0 ----
    {
        const float* xt = X + row00 * 256;
        #pragma unroll
        for (int j = 0; j < 4; ++j) {
            const int r = w * 4 + j;                       // wave stages rows 4w..4w+3
            const u32 bo = ((u32)(l * 16)) ^ ((u32)(r & 7) << 4);
            __builtin_amdgcn_global_load_lds(
                (const __attribute__((address_space(1))) void*)(xt + r * 256 + (bo >> 2)),
                (__attribute__((address_space(3))) void*)&Xs[0][r * 256], 16, 0, 0);
        }
    }
    asm volatile("s_waitcnt vmcnt(0)" ::: "memory");
    __builtin_amdgcn_s_barrier();

    for (int t = 0; t < T_TILES; ++t) {
        // ---- issue DMA for tile t+1 first; it completes under this tile's compute ----
        if (t + 1 < T_TILES) {
            const float* xt = X + (row00 + (size_t)(t + 1) * 16) * 256;
            float* dstbuf = &Xs[(t + 1) & 1][0];
            #pragma unroll
            for (int j = 0; j < 4; ++j) {
                const int r = w * 4 + j;
                const u32 bo = ((u32)(l * 16)) ^ ((u32)(r & 7) << 4);
                __builtin_amdgcn_global_load_lds(
                    (const __attribute__((address_space(1))) void*)(xt + r * 256 + (bo >> 2)),
                    (__attribute__((address_space(3))) void*)(dstbuf + r * 256), 16, 0, 0);
            }
        }

        // ---- read f32 + quantize -> A fragments in registers ----
        const char* base = (const char*)&Xs[t & 1][0] + lr * 1024;
        const u32 swz = (u32)(lr & 7) << 4;
        bf16x8 af[8];
        #pragma unroll
        for (int ks = 0; ks < 8; ++ks) {
            const u32 c  = (u32)(ks * 128 + lg * 32);
            const float4 v0 = *(const float4*)(base + (c ^ swz));
            const float4 v1 = *(const float4*)(base + ((c + 16) ^ swz));
            float am = fmaxf(fmaxf(fabsf(v0.x), fabsf(v0.y)), fmaxf(fabsf(v0.z), fabsf(v0.w)));
            am = fmaxf(am, fmaxf(fmaxf(fabsf(v1.x), fabsf(v1.y)), fmaxf(fabsf(v1.z), fabsf(v1.w))));
            am = fmaxf(am, __shfl_xor(am, 16));   // other lg lanes, same row
            am = fmaxf(am, __shfl_xor(am, 32));
            float sc, inv; block_scale(am, sc, inv);
            const u16x4 q0 = quant4(v0, inv, sc);
            const u16x4 q1 = quant4(v1, inv, sc);
            bf16x8 a;
            a[0] = (short)q0.x; a[1] = (short)q0.y; a[2] = (short)q0.z; a[3] = (short)q0.w;
            a[4] = (short)q1.x; a[5] = (short)q1.y; a[6] = (short)q1.z; a[7] = (short)q1.w;
            af[ks] = a;
        }

        // ---- reg-only MFMA burst: 4 independent acc chains ----
        __builtin_amdgcn_s_setprio(1);
        f32x4 acc[4] = {};
        #pragma unroll
        for (int ks = 0; ks < 8; ++ks)
            #pragma unroll
            for (int ct = 0; ct < 4; ++ct)
                acc[ct] = __builtin_amdgcn_mfma_f32_16x16x32_bf16(
                    breg[ct][ks], af[ks], acc[ct], 0, 0, 0);
        __builtin_amdgcn_s_setprio(0);

        // ---- epilogue: lane holds C[row=lr][col=w*64+ct*16+lg*4 ..+3] ----
        const size_t row0 = row00 + (size_t)t * 16;
        #pragma unroll
        for (int ct = 0; ct < 4; ++ct) {
            f32x4 o = acc[ct];
            o[0] += bv[ct].x; o[1] += bv[ct].y; o[2] += bv[ct].z; o[3] += bv[ct].w;
            *(f32x4*)(out + (row0 + lr) * 256 + w * 64 + ct * 16 + lg * 4) = o;
        }

        // ---- drain DMA(t+1) + stores, sync buffer swap ----
        asm volatile("s_waitcnt vmcnt(0) lgkmcnt(0)" ::: "memory");
        __builtin_amdgcn_s_barrier();
    }
}

extern "C" void kernel_launch(void* const* d_in, const int* in_sizes, int n_in,
                              void* d_out, int out_size, void* d_ws, size_t ws_size,
                              hipStream_t stream) {
    const float* x    = (const float*)d_in[0];
    const float* wk   = (const float*)d_in[1];
    const float* bias = (const float*)d_in[2];
    float* out = (float*)d_out;
    u16* Bq    = (u16*)d_ws;                  // 256*256 bf16 = 128 KB scratch
    const int M = in_sizes[0] / 256;          // 131072 rows
    (void)M;
    wq_kernel<<<64, 256, 0, stream>>>(wk, Bq);
    mx_gemm<<<NBLK, 256, 0, stream>>>(x, Bq, bias, out);
}

// Round 7
// 85.226 us; speedup vs baseline: 1.5731x; 1.0677x over previous
//
#include <hip/hip_runtime.h>
#include <hip/hip_bf16.h>

typedef unsigned short u16;
typedef unsigned int u32;
typedef __attribute__((ext_vector_type(8))) short bf16x8;
typedef __attribute__((ext_vector_type(4))) float f32x4;
typedef __attribute__((ext_vector_type(2))) float f32x2;
typedef __attribute__((ext_vector_type(4))) unsigned short u16x4;

#define T_TILES 8    // 16-row tiles per block
#define NBLK    1024 // 1024 * 8 * 16 = 131072 rows

// shared_exp = floor(log2(amax)) - 8 ; scale = 2^shared_exp (power of two)
__device__ __forceinline__ void block_scale(float amax, float& scale, float& inv_scale) {
    int be = (int)(__float_as_uint(amax) >> 23);   // biased exponent, amax >= 0
    be = be < 8 ? 8 : be;                          // tiny/zero blocks quantize to 0 anyway
    scale     = __uint_as_float((unsigned)(be - 8) << 23);   // 2^(be-135)
    inv_scale = __uint_as_float((unsigned)(262 - be) << 23); // 2^(135-be)
}

#if __has_builtin(__builtin_amdgcn_cvt_pk_fp8_f32) && __has_builtin(__builtin_amdgcn_cvt_pk_f32_fp8)
#define HAS_HW_FP8 1
#else
#define HAS_HW_FP8 0
#endif

#if !HAS_HW_FP8
// Fallback: exact bit-math e4m3 RNE (verified in round 0)
__device__ __forceinline__ float mx_e4m3(float x, float inv_scale, float scale) {
    float v  = x * inv_scale;
    float av = fabsf(v);
    int e = (int)(__float_as_uint(av) >> 23) - 127;
    e = e < -6 ? -6 : (e > 8 ? 8 : e);
    float qs = __uint_as_float((unsigned)(130 - e) << 23);
    float qm = __uint_as_float((unsigned)(124 + e) << 23);
    float q  = fminf(rintf(av * qs) * qm, 448.0f);
    return copysignf(q, v) * scale;
}
#endif

// Quantize 4 elems to e4m3 grid (RNE, saturate 448), return bf16 bits of value*scale.
// bf16 conversion is exact (e4m3: 4 significand bits; bf16: 8).
__device__ __forceinline__ u16x4 quant4(float4 v, float inv, float sc) {
    u16x4 r;
#if HAS_HW_FP8
    float a = fminf(fmaxf(v.x * inv, -448.f), 448.f);
    float b = fminf(fmaxf(v.y * inv, -448.f), 448.f);
    float c = fminf(fmaxf(v.z * inv, -448.f), 448.f);
    float d = fminf(fmaxf(v.w * inv, -448.f), 448.f);
    int p = __builtin_amdgcn_cvt_pk_fp8_f32(a, b, 0, false);   // RNE f32->e4m3 (OCP)
    p     = __builtin_amdgcn_cvt_pk_fp8_f32(c, d, p, true);
    f32x2 lo = __builtin_amdgcn_cvt_pk_f32_fp8(p, false);      // exact e4m3->f32
    f32x2 hi = __builtin_amdgcn_cvt_pk_f32_fp8(p, true);
    r.x = (u16)(__float_as_uint(lo[0] * sc) >> 16);
    r.y = (u16)(__float_as_uint(lo[1] * sc) >> 16);
    r.z = (u16)(__float_as_uint(hi[0] * sc) >> 16);
    r.w = (u16)(__float_as_uint(hi[1] * sc) >> 16);
#else
    r.x = (u16)(__float_as_uint(mx_e4m3(v.x, inv, sc)) >> 16);
    r.y = (u16)(__float_as_uint(mx_e4m3(v.y, inv, sc)) >> 16);
    r.z = (u16)(__float_as_uint(mx_e4m3(v.z, inv, sc)) >> 16);
    r.w = (u16)(__float_as_uint(mx_e4m3(v.w, inv, sc)) >> 16);
#endif
    return r;
}

// Quantize 256x256 weight to bf16 fake-quant, stored TRANSPOSED: Bq[n*256+k].
// MX blocks are 32 consecutive n at fixed k (flat reshape of row-major (K,N)).
__global__ void wq_kernel(const float* __restrict__ W, u16* __restrict__ Bq) {
    const int t  = blockIdx.x * blockDim.x + threadIdx.x;
    const int f  = t * 4;
    const int k  = f >> 8;
    const int n0 = f & 255;
    const float4 v = *(const float4*)(W + f);
    float am = fmaxf(fmaxf(fabsf(v.x), fabsf(v.y)), fmaxf(fabsf(v.z), fabsf(v.w)));
    am = fmaxf(am, __shfl_xor(am, 1));   // 8 lanes x 4 elems = one 32-elem MX block
    am = fmaxf(am, __shfl_xor(am, 2));
    am = fmaxf(am, __shfl_xor(am, 4));
    float sc, inv; block_scale(am, sc, inv);
    u16x4 q = quant4(v, inv, sc);
    Bq[(size_t)(n0 + 0) * 256 + k] = q.x;
    Bq[(size_t)(n0 + 1) * 256 + k] = q.y;
    Bq[(size_t)(n0 + 2) * 256 + k] = q.z;
    Bq[(size_t)(n0 + 3) * 256 + k] = q.w;
}

// T4 counted-vmcnt pipeline: 3 LDS buffers, DMA issued 2 tiles ahead, vmcnt
// NEVER drained to 0 in the loop. Per wave per iter: 4 DMA + 4 stores.
// At iter t's wait (need DMA(t+1) complete), ops newer than DMA(t+1):
//   stores(t-1) [4, t>0] + DMA(t+2) [4, if t+2<T] + stores(t) [4]
// -> vmcnt(8) at t==0, vmcnt(12) for 1<=t<=T-3, vmcnt(8) at t==T-2, none at T-1.
__global__ void __launch_bounds__(256, 2)
mx_gemm(const float* __restrict__ X, const u16* __restrict__ Bq,
        const float* __restrict__ bias, float* __restrict__ out)
{
    __shared__ float Xs[3][16 * 256];    // 3 x 16 KB raw f32, linear layout
    const int tid = threadIdx.x;
    const int w   = tid >> 6;
    const int l   = tid & 63;
    const int lr  = l & 15;
    const int lg  = l >> 4;
    const size_t row00 = (size_t)blockIdx.x * (16 * T_TILES);
    const float* xbase = X + row00 * 256;

    // ---- B slice -> registers (128 VGPRs), bias -> registers ----
    bf16x8 breg[4][8];
    {
        const u16* bb = Bq + (size_t)(w * 64 + lr) * 256 + lg * 8;
        #pragma unroll
        for (int ct = 0; ct < 4; ++ct)
            #pragma unroll
            for (int ks = 0; ks < 8; ++ks)
                breg[ct][ks] = *(const bf16x8*)(bb + (size_t)ct * 16 * 256 + ks * 32);
    }
    float4 bv[4];
    #pragma unroll
    for (int ct = 0; ct < 4; ++ct)
        bv[ct] = *(const float4*)(bias + w * 64 + ct * 16 + lg * 4);

    // ---- prologue: stage tiles 0 and 1; wait only for tile 0 (vmcnt(4)) ----
    #pragma unroll
    for (int pt = 0; pt < 2; ++pt) {
        const float* xt = xbase + (size_t)pt * 16 * 256;
        #pragma unroll
        for (int j = 0; j < 4; ++j) {
            const int r = w * 4 + j;                       // wave stages rows 4w..4w+3
            __builtin_amdgcn_global_load_lds(
                (const __attribute__((address_space(1))) void*)(xt + r * 256 + l * 4),
                (__attribute__((address_space(3))) void*)&Xs[pt][r * 256], 16, 0, 0);
        }
    }
    asm volatile("s_waitcnt vmcnt(4)" ::: "memory");
    __builtin_amdgcn_s_barrier();

    #pragma unroll
    for (int t = 0; t < T_TILES; ++t) {
        // ---- issue DMA for tile t+2 (stays in flight under 2 tiles of compute) ----
        if (t + 2 < T_TILES) {
            const float* xt = xbase + (size_t)(t + 2) * 16 * 256;
            float* dst = &Xs[(t + 2) % 3][0];
            #pragma unroll
            for (int j = 0; j < 4; ++j) {
                const int r = w * 4 + j;
                __builtin_amdgcn_global_load_lds(
                    (const __attribute__((address_space(1))) void*)(xt + r * 256 + l * 4),
                    (__attribute__((address_space(3))) void*)(dst + r * 256), 16, 0, 0);
            }
        }
        __builtin_amdgcn_sched_barrier(0);   // pin DMA issue above compute

        // ---- quantize tile t from LDS -> A fragments (linear reads) ----
        const float* base = &Xs[t % 3][0] + lr * 256;
        bf16x8 af[8];
        #pragma unroll
        for (int ks = 0; ks < 8; ++ks) {
            const float4 v0 = *(const float4*)(base + ks * 32 + lg * 8);
            const float4 v1 = *(const float4*)(base + ks * 32 + lg * 8 + 4);
            float am = fmaxf(fmaxf(fabsf(v0.x), fabsf(v0.y)), fmaxf(fabsf(v0.z), fabsf(v0.w)));
            am = fmaxf(am, fmaxf(fmaxf(fabsf(v1.x), fabsf(v1.y)), fmaxf(fabsf(v1.z), fabsf(v1.w))));
            am = fmaxf(am, __shfl_xor(am, 16));   // other lg lanes, same row: one 32-k MX block
            am = fmaxf(am, __shfl_xor(am, 32));
            float sc, inv; block_scale(am, sc, inv);
            const u16x4 q0 = quant4(v0, inv, sc);
            const u16x4 q1 = quant4(v1, inv, sc);
            bf16x8 a;
            a[0] = (short)q0.x; a[1] = (short)q0.y; a[2] = (short)q0.z; a[3] = (short)q0.w;
            a[4] = (short)q1.x; a[5] = (short)q1.y; a[6] = (short)q1.z; a[7] = (short)q1.w;
            af[ks] = a;
        }

        // ---- reg-only MFMA burst ----
        __builtin_amdgcn_s_setprio(1);
        f32x4 acc[4] = {};
        #pragma unroll
        for (int ks = 0; ks < 8; ++ks)
            #pragma unroll
            for (int ct = 0; ct < 4; ++ct)
                acc[ct] = __builtin_amdgcn_mfma_f32_16x16x32_bf16(
                    breg[ct][ks], af[ks], acc[ct], 0, 0, 0);
        __builtin_amdgcn_s_setprio(0);

        // ---- stores: lane holds C[row=lr][col=w*64+ct*16+lg*4 ..+3] ----
        const size_t row0 = row00 + (size_t)t * 16;
        #pragma unroll
        for (int ct = 0; ct < 4; ++ct) {
            f32x4 o = acc[ct];
            o[0] += bv[ct].x; o[1] += bv[ct].y; o[2] += bv[ct].z; o[3] += bv[ct].w;
            *(f32x4*)(out + (row0 + lr) * 256 + w * 64 + ct * 16 + lg * 4) = o;
        }

        // ---- counted wait: ensure DMA(t+1) done; never drain to 0 ----
        if (t + 1 < T_TILES) {
            if (t == 0)
                asm volatile("s_waitcnt vmcnt(8)" ::: "memory");
            else if (t + 2 < T_TILES)
                asm volatile("s_waitcnt vmcnt(12)" ::: "memory");
            else
                asm volatile("s_waitcnt vmcnt(8)" ::: "memory");
            __builtin_amdgcn_s_barrier();
        }
    }
}

extern "C" void kernel_launch(void* const* d_in, const int* in_sizes, int n_in,
                              void* d_out, int out_size, void* d_ws, size_t ws_size,
                              hipStream_t stream) {
    const float* x    = (const float*)d_in[0];
    const float* wk   = (const float*)d_in[1];
    const float* bias = (const float*)d_in[2];
    float* out = (float*)d_out;
    u16* Bq    = (u16*)d_ws;                  // 256*256 bf16 = 128 KB scratch
    wq_kernel<<<64, 256, 0, stream>>>(wk, Bq);
    mx_gemm<<<NBLK, 256, 0, stream>>>(x, Bq, bias, out);
}

// Round 8
// 69.960 us; speedup vs baseline: 1.9164x; 1.2182x over previous
//
#include <hip/hip_runtime.h>
#include <hip/hip_bf16.h>

typedef unsigned short u16;
typedef unsigned int u32;
typedef __attribute__((ext_vector_type(8))) short bf16x8;
typedef __attribute__((ext_vector_type(4))) float f32x4;
typedef __attribute__((ext_vector_type(2))) float f32x2;
typedef __attribute__((ext_vector_type(4))) unsigned short u16x4;

#define T_TILES 16   // 16-row tiles per block
#define NBLK    512  // 512 * 16 * 16 = 131072 rows; exactly 2 blocks/CU

// shared_exp = floor(log2(amax)) - 8 ; scale = 2^shared_exp (power of two)
__device__ __forceinline__ void block_scale(float amax, float& scale, float& inv_scale) {
    int be = (int)(__float_as_uint(amax) >> 23);   // biased exponent, amax >= 0
    be = be < 8 ? 8 : be;                          // tiny/zero blocks quantize to 0 anyway
    scale     = __uint_as_float((unsigned)(be - 8) << 23);   // 2^(be-135)
    inv_scale = __uint_as_float((unsigned)(262 - be) << 23); // 2^(135-be)
}

#if __has_builtin(__builtin_amdgcn_cvt_pk_fp8_f32) && __has_builtin(__builtin_amdgcn_cvt_pk_f32_fp8)
#define HAS_HW_FP8 1
#else
#define HAS_HW_FP8 0
#endif

#if !HAS_HW_FP8
// Fallback: exact bit-math e4m3 RNE (verified in round 0)
__device__ __forceinline__ float mx_e4m3(float x, float inv_scale, float scale) {
    float v  = x * inv_scale;
    float av = fabsf(v);
    int e = (int)(__float_as_uint(av) >> 23) - 127;
    e = e < -6 ? -6 : (e > 8 ? 8 : e);
    float qs = __uint_as_float((unsigned)(130 - e) << 23);
    float qm = __uint_as_float((unsigned)(124 + e) << 23);
    float q  = fminf(rintf(av * qs) * qm, 448.0f);
    return copysignf(q, v) * scale;
}
#endif

// Quantize 4 elems to e4m3 grid (RNE, saturate 448), return bf16 bits of value*scale.
__device__ __forceinline__ u16x4 quant4(float4 v, float inv, float sc) {
    u16x4 r;
#if HAS_HW_FP8
    float a = fminf(fmaxf(v.x * inv, -448.f), 448.f);
    float b = fminf(fmaxf(v.y * inv, -448.f), 448.f);
    float c = fminf(fmaxf(v.z * inv, -448.f), 448.f);
    float d = fminf(fmaxf(v.w * inv, -448.f), 448.f);
    int p = __builtin_amdgcn_cvt_pk_fp8_f32(a, b, 0, false);   // RNE f32->e4m3 (OCP)
    p     = __builtin_amdgcn_cvt_pk_fp8_f32(c, d, p, true);
    f32x2 lo = __builtin_amdgcn_cvt_pk_f32_fp8(p, false);      // exact e4m3->f32
    f32x2 hi = __builtin_amdgcn_cvt_pk_f32_fp8(p, true);
    r.x = (u16)(__float_as_uint(lo[0] * sc) >> 16);
    r.y = (u16)(__float_as_uint(lo[1] * sc) >> 16);
    r.z = (u16)(__float_as_uint(hi[0] * sc) >> 16);
    r.w = (u16)(__float_as_uint(hi[1] * sc) >> 16);
#else
    r.x = (u16)(__float_as_uint(mx_e4m3(v.x, inv, sc)) >> 16);
    r.y = (u16)(__float_as_uint(mx_e4m3(v.y, inv, sc)) >> 16);
    r.z = (u16)(__float_as_uint(mx_e4m3(v.z, inv, sc)) >> 16);
    r.w = (u16)(__float_as_uint(mx_e4m3(v.w, inv, sc)) >> 16);
#endif
    return r;
}

// Quantize 256x256 weight to bf16 fake-quant, stored TRANSPOSED: Bq[n*256+k].
__global__ void wq_kernel(const float* __restrict__ W, u16* __restrict__ Bq) {
    const int t  = blockIdx.x * blockDim.x + threadIdx.x;
    const int f  = t * 4;
    const int k  = f >> 8;
    const int n0 = f & 255;
    const float4 v = *(const float4*)(W + f);
    float am = fmaxf(fmaxf(fabsf(v.x), fabsf(v.y)), fmaxf(fabsf(v.z), fabsf(v.w)));
    am = fmaxf(am, __shfl_xor(am, 1));   // 8 lanes x 4 elems = one 32-elem MX block
    am = fmaxf(am, __shfl_xor(am, 2));
    am = fmaxf(am, __shfl_xor(am, 4));
    float sc, inv; block_scale(am, sc, inv);
    u16x4 q = quant4(v, inv, sc);
    Bq[(size_t)(n0 + 0) * 256 + k] = q.x;
    Bq[(size_t)(n0 + 1) * 256 + k] = q.y;
    Bq[(size_t)(n0 + 2) * 256 + k] = q.z;
    Bq[(size_t)(n0 + 3) * 256 + k] = q.w;
}

// Duty-cycle pipeline: f32 X in a 3-slot DMA ring (issued 2 tiles ahead, counted
// vmcnt, NEVER drained); wave w stages+quantizes ONLY rows 4w..4w+3 (wave-private
// -> own vmcnt suffices, no barrier before quant; ring WAR-safe by program order).
// Shared Aq bf16 tile double-buffered -> exactly ONE raw s_barrier per iter with
// lgkmcnt(0) only (vmcnt stays in flight across it).
// Per wave per iter vm-ops: 4 DMA + 4 stores. At iter t's wait (DMA(t) complete),
// newer ops: DMA(t+1)[t+1<T] + stores(t-1)[t>0] + DMA(t+2)[t+2<T]:
//   t=0 -> 8 ; 1<=t<=T-3 -> 12 ; t=T-2 -> 8 ; t=T-1 -> 4.
__global__ void __launch_bounds__(256, 2)
mx_gemm(const float* __restrict__ X, const u16* __restrict__ Bq,
        const float* __restrict__ bias, float* __restrict__ out)
{
    __shared__ float Xf[3][16 * 256];    // 48 KB f32 ring, linear wave-private slots
    __shared__ u16   Aq[2][16 * 256];    // 16 KB bf16 fake-quant tile, XOR-swizzled
    const int tid = threadIdx.x;
    const int w   = tid >> 6;
    const int l   = tid & 63;
    const int lr  = l & 15;
    const int lg  = l >> 4;
    const size_t row00 = (size_t)blockIdx.x * (16 * T_TILES);
    const float* xbase = X + row00 * 256;

    // ---- B slice -> registers (128 VGPRs), bias -> registers ----
    bf16x8 breg[4][8];
    {
        const u16* bb = Bq + (size_t)(w * 64 + lr) * 256 + lg * 8;
        #pragma unroll
        for (int ct = 0; ct < 4; ++ct)
            #pragma unroll
            for (int ks = 0; ks < 8; ++ks)
                breg[ct][ks] = *(const bf16x8*)(bb + (size_t)ct * 16 * 256 + ks * 32);
    }
    float4 bv[4];
    #pragma unroll
    for (int ct = 0; ct < 4; ++ct)
        bv[ct] = *(const float4*)(bias + w * 64 + ct * 16 + lg * 4);

    // ---- prologue: DMA tiles 0 and 1 (wave-private rows 4w..4w+3) ----
    #pragma unroll
    for (int pt = 0; pt < 2; ++pt) {
        #pragma unroll
        for (int j = 0; j < 4; ++j) {
            const int r = w * 4 + j;
            __builtin_amdgcn_global_load_lds(
                (const __attribute__((address_space(1))) void*)(xbase + (size_t)(pt * 16 + r) * 256 + l * 4),
                (__attribute__((address_space(3))) void*)&Xf[pt][r * 256], 16, 0, 0);
        }
    }

    int slot = 0;   // t % 3
    #pragma unroll 1
    for (int t = 0; t < T_TILES; ++t) {
        // ---- issue DMA for tile t+2 into slot (t+2)%3 (overwrites t-1's slot:
        //      wave-private rows already consumed by OUR quant(t-1), safe) ----
        if (t + 2 < T_TILES) {
            const int s2 = slot >= 1 ? slot - 1 : slot + 2;   // (t+2)%3
            #pragma unroll
            for (int j = 0; j < 4; ++j) {
                const int r = w * 4 + j;
                __builtin_amdgcn_global_load_lds(
                    (const __attribute__((address_space(1))) void*)(xbase + (size_t)((t + 2) * 16 + r) * 256 + l * 4),
                    (__attribute__((address_space(3))) void*)&Xf[s2][r * 256], 16, 0, 0);
            }
        }

        // ---- counted wait: OWN DMA(t) complete; keep the rest in flight ----
        if (t == 0 || t == T_TILES - 2)
            asm volatile("s_waitcnt vmcnt(8)" ::: "memory");
        else if (t == T_TILES - 1)
            asm volatile("s_waitcnt vmcnt(4)" ::: "memory");
        else
            asm volatile("s_waitcnt vmcnt(12)" ::: "memory");
        __builtin_amdgcn_sched_barrier(0);

        // ---- quantize OWN 4 rows from f32 ring -> swizzled bf16 Aq[t&1] ----
        {
            u16* aqb = &Aq[t & 1][0];
            const float* xs = &Xf[slot][0];
            #pragma unroll
            for (int j = 0; j < 4; ++j) {
                const int r = w * 4 + j;
                const float4 v = *(const float4*)(xs + r * 256 + l * 4);
                float am = fmaxf(fmaxf(fabsf(v.x), fabsf(v.y)), fmaxf(fabsf(v.z), fabsf(v.w)));
                am = fmaxf(am, __shfl_xor(am, 1));  // 8-lane group = one 32-elem MX block
                am = fmaxf(am, __shfl_xor(am, 2));
                am = fmaxf(am, __shfl_xor(am, 4));
                float sc, inv; block_scale(am, sc, inv);
                u16x4 q = quant4(v, inv, sc);
                char* dst = (char*)aqb + (((u32)(r * 512 + l * 8)) ^ ((u32)(r & 7) << 4));
                *(u16x4*)dst = q;
            }
        }

        // ---- ONE barrier: Aq visible to all waves; vmcnt NOT drained ----
        asm volatile("s_waitcnt lgkmcnt(0)" ::: "memory");
        __builtin_amdgcn_s_barrier();

        // ---- MFMA: af from swizzled Aq, reg-only burst ----
        const char* ab = (const char*)&Aq[t & 1][0];
        const u32 swz = (u32)(lr & 7) << 4;
        bf16x8 af[8];
        #pragma unroll
        for (int ks = 0; ks < 8; ++ks)
            af[ks] = *(const bf16x8*)(ab + (((u32)(lr * 512 + ks * 64 + lg * 16)) ^ swz));

        __builtin_amdgcn_s_setprio(1);
        f32x4 acc[4] = {};
        #pragma unroll
        for (int ks = 0; ks < 8; ++ks)
            #pragma unroll
            for (int ct = 0; ct < 4; ++ct)
                acc[ct] = __builtin_amdgcn_mfma_f32_16x16x32_bf16(
                    breg[ct][ks], af[ks], acc[ct], 0, 0, 0);
        __builtin_amdgcn_s_setprio(0);

        // ---- stores: lane holds C[row=lr][col=w*64+ct*16+lg*4 ..+3] ----
        const size_t row0 = row00 + (size_t)t * 16;
        #pragma unroll
        for (int ct = 0; ct < 4; ++ct) {
            f32x4 o = acc[ct];
            o[0] += bv[ct].x; o[1] += bv[ct].y; o[2] += bv[ct].z; o[3] += bv[ct].w;
            *(f32x4*)(out + (row0 + lr) * 256 + w * 64 + ct * 16 + lg * 4) = o;
        }

        slot = slot == 2 ? 0 : slot + 1;
        // No second barrier: MFMA(t) reads Aq[t&1]; the next write to that buffer
        // is quant(t+2), which is after barrier(t+1) -> max skew 1 iter, safe.
    }
}

extern "C" void kernel_launch(void* const* d_in, const int* in_sizes, int n_in,
                              void* d_out, int out_size, void* d_ws, size_t ws_size,
                              hipStream_t stream) {
    const float* x    = (const float*)d_in[0];
    const float* wk   = (const float*)d_in[1];
    const float* bias = (const float*)d_in[2];
    float* out = (float*)d_out;
    u16* Bq    = (u16*)d_ws;                  // 256*256 bf16 = 128 KB scratch
    wq_kernel<<<64, 256, 0, stream>>>(wk, Bq);
    mx_gemm<<<NBLK, 256, 0, stream>>>(x, Bq, bias, out);
}

// Round 9
// 67.199 us; speedup vs baseline: 1.9951x; 1.0411x over previous
//
#include <hip/hip_runtime.h>
#include <hip/hip_bf16.h>

typedef unsigned short u16;
typedef unsigned int u32;
typedef __attribute__((ext_vector_type(8))) short bf16x8;
typedef __attribute__((ext_vector_type(4))) float f32x4;
typedef __attribute__((ext_vector_type(2))) float f32x2;
typedef __attribute__((ext_vector_type(4))) unsigned short u16x4;

#define T_TILES 16   // 16-row tiles per block
#define NBLK    512  // 512 * 16 * 16 = 131072 rows; 2 blocks/CU

// shared_exp = floor(log2(amax)) - 8 ; scale = 2^shared_exp (power of two)
__device__ __forceinline__ void block_scale(float amax, float& scale, float& inv_scale) {
    int be = (int)(__float_as_uint(amax) >> 23);   // biased exponent, amax >= 0
    be = be < 8 ? 8 : be;                          // tiny/zero blocks quantize to 0 anyway
    scale     = __uint_as_float((unsigned)(be - 8) << 23);   // 2^(be-135)
    inv_scale = __uint_as_float((unsigned)(262 - be) << 23); // 2^(135-be)
}

#if __has_builtin(__builtin_amdgcn_cvt_pk_fp8_f32) && __has_builtin(__builtin_amdgcn_cvt_pk_f32_fp8)
#define HAS_HW_FP8 1
#else
#define HAS_HW_FP8 0
#endif

#if !HAS_HW_FP8
// Fallback: exact bit-math e4m3 RNE (verified in round 0)
__device__ __forceinline__ float mx_e4m3(float x, float inv_scale, float scale) {
    float v  = x * inv_scale;
    float av = fabsf(v);
    int e = (int)(__float_as_uint(av) >> 23) - 127;
    e = e < -6 ? -6 : (e > 8 ? 8 : e);
    float qs = __uint_as_float((unsigned)(130 - e) << 23);
    float qm = __uint_as_float((unsigned)(124 + e) << 23);
    float q  = fminf(rintf(av * qs) * qm, 448.0f);
    return copysignf(q, v) * scale;
}
#endif

// Quantize 4 elems to e4m3 grid (RNE, saturate 448), return bf16 bits of value*scale.
__device__ __forceinline__ u16x4 quant4(float4 v, float inv, float sc) {
    u16x4 r;
#if HAS_HW_FP8
    float a = fminf(fmaxf(v.x * inv, -448.f), 448.f);
    float b = fminf(fmaxf(v.y * inv, -448.f), 448.f);
    float c = fminf(fmaxf(v.z * inv, -448.f), 448.f);
    float d = fminf(fmaxf(v.w * inv, -448.f), 448.f);
    int p = __builtin_amdgcn_cvt_pk_fp8_f32(a, b, 0, false);   // RNE f32->e4m3 (OCP)
    p     = __builtin_amdgcn_cvt_pk_fp8_f32(c, d, p, true);
    f32x2 lo = __builtin_amdgcn_cvt_pk_f32_fp8(p, false);      // exact e4m3->f32
    f32x2 hi = __builtin_amdgcn_cvt_pk_f32_fp8(p, true);
    r.x = (u16)(__float_as_uint(lo[0] * sc) >> 16);
    r.y = (u16)(__float_as_uint(lo[1] * sc) >> 16);
    r.z = (u16)(__float_as_uint(hi[0] * sc) >> 16);
    r.w = (u16)(__float_as_uint(hi[1] * sc) >> 16);
#else
    r.x = (u16)(__float_as_uint(mx_e4m3(v.x, inv, sc)) >> 16);
    r.y = (u16)(__float_as_uint(mx_e4m3(v.y, inv, sc)) >> 16);
    r.z = (u16)(__float_as_uint(mx_e4m3(v.z, inv, sc)) >> 16);
    r.w = (u16)(__float_as_uint(mx_e4m3(v.w, inv, sc)) >> 16);
#endif
    return r;
}

// Quantize 256x256 weight to bf16 fake-quant, stored TRANSPOSED: Bq[n*256+k].
__global__ void wq_kernel(const float* __restrict__ W, u16* __restrict__ Bq) {
    const int t  = blockIdx.x * blockDim.x + threadIdx.x;
    const int f  = t * 4;
    const int k  = f >> 8;
    const int n0 = f & 255;
    const float4 v = *(const float4*)(W + f);
    float am = fmaxf(fmaxf(fabsf(v.x), fabsf(v.y)), fmaxf(fabsf(v.z), fabsf(v.w)));
    am = fmaxf(am, __shfl_xor(am, 1));   // 8 lanes x 4 elems = one 32-elem MX block
    am = fmaxf(am, __shfl_xor(am, 2));
    am = fmaxf(am, __shfl_xor(am, 4));
    float sc, inv; block_scale(am, sc, inv);
    u16x4 q = quant4(v, inv, sc);
    Bq[(size_t)(n0 + 0) * 256 + k] = q.x;
    Bq[(size_t)(n0 + 1) * 256 + k] = q.y;
    Bq[(size_t)(n0 + 2) * 256 + k] = q.z;
    Bq[(size_t)(n0 + 3) * 256 + k] = q.w;
}

// Register-staged pipeline (no f32 LDS, no DMA):
//  - wave w loads ONLY its 4 private rows per tile as plain float4 loads into
//    a double-buffered register tile xv[2][4] (statically indexed, full unroll)
//    -> compiler inserts exact counted vmcnt waits; 2 tiles of loads in flight.
//  - quantize straight from load registers (identical math/layout to R8:
//    row r = 4w+j, cols l*4; amax over 8-lane group = one 32-elem MX block),
//    write bf16 to XOR-swizzled Aq double buffer.
//  - ONE raw s_barrier + lgkmcnt(0) per tile (raw barrier => NO vmcnt drain).
//  - MFMA burst is reg-only (B slice in 128 VGPRs, loaded once from L2).
__global__ void __launch_bounds__(256, 2)
mx_gemm(const float* __restrict__ X, const u16* __restrict__ Bq,
        const float* __restrict__ bias, float* __restrict__ out)
{
    __shared__ u16 Aq[2][16 * 256];      // 2 x 8 KB bf16, XOR-swizzled
    const int tid = threadIdx.x;
    const int w   = tid >> 6;
    const int l   = tid & 63;
    const int lr  = l & 15;
    const int lg  = l >> 4;
    const size_t row00 = (size_t)blockIdx.x * (16 * T_TILES);
    const float* xbase = X + row00 * 256;

    // ---- B slice -> registers (128 VGPRs), bias -> registers ----
    bf16x8 breg[4][8];
    {
        const u16* bb = Bq + (size_t)(w * 64 + lr) * 256 + lg * 8;
        #pragma unroll
        for (int ct = 0; ct < 4; ++ct)
            #pragma unroll
            for (int ks = 0; ks < 8; ++ks)
                breg[ct][ks] = *(const bf16x8*)(bb + (size_t)ct * 16 * 256 + ks * 32);
    }
    float4 bv[4];
    #pragma unroll
    for (int ct = 0; ct < 4; ++ct)
        bv[ct] = *(const float4*)(bias + w * 64 + ct * 16 + lg * 4);

    // ---- prologue: load tiles 0 and 1 into register buffers ----
    float4 xv[2][4];
    #pragma unroll
    for (int pt = 0; pt < 2; ++pt)
        #pragma unroll
        for (int j = 0; j < 4; ++j)
            xv[pt][j] = *(const float4*)(xbase + (size_t)(pt * 16 + w * 4 + j) * 256 + l * 4);

    #pragma unroll
    for (int t = 0; t < T_TILES; ++t) {
        // ---- quantize own 4 rows from registers -> swizzled bf16 Aq[t&1] ----
        {
            u16* aqb = &Aq[t & 1][0];
            #pragma unroll
            for (int j = 0; j < 4; ++j) {
                const int r = w * 4 + j;
                const float4 v = xv[t & 1][j];
                float am = fmaxf(fmaxf(fabsf(v.x), fabsf(v.y)), fmaxf(fabsf(v.z), fabsf(v.w)));
                am = fmaxf(am, __shfl_xor(am, 1));  // 8-lane group = one 32-elem MX block
                am = fmaxf(am, __shfl_xor(am, 2));
                am = fmaxf(am, __shfl_xor(am, 4));
                float sc, inv; block_scale(am, sc, inv);
                u16x4 q = quant4(v, inv, sc);
                char* dst = (char*)aqb + (((u32)(r * 512 + l * 8)) ^ ((u32)(r & 7) << 4));
                *(u16x4*)dst = q;
            }
        }

        // ---- refill the just-freed register buffer with tile t+2 ----
        if (t + 2 < T_TILES) {
            #pragma unroll
            for (int j = 0; j < 4; ++j)
                xv[t & 1][j] = *(const float4*)(xbase + (size_t)((t + 2) * 16 + w * 4 + j) * 256 + l * 4);
        }
        __builtin_amdgcn_sched_barrier(0);   // pin prefetch issue above the barrier

        // ---- ONE barrier: Aq visible to all waves; vmcnt stays in flight ----
        asm volatile("s_waitcnt lgkmcnt(0)" ::: "memory");
        __builtin_amdgcn_s_barrier();

        // ---- MFMA: af from swizzled Aq, reg-only burst ----
        const char* ab = (const char*)&Aq[t & 1][0];
        const u32 swz = (u32)(lr & 7) << 4;
        bf16x8 af[8];
        #pragma unroll
        for (int ks = 0; ks < 8; ++ks)
            af[ks] = *(const bf16x8*)(ab + (((u32)(lr * 512 + ks * 64 + lg * 16)) ^ swz));

        __builtin_amdgcn_s_setprio(1);
        f32x4 acc[4] = {};
        #pragma unroll
        for (int ks = 0; ks < 8; ++ks)
            #pragma unroll
            for (int ct = 0; ct < 4; ++ct)
                acc[ct] = __builtin_amdgcn_mfma_f32_16x16x32_bf16(
                    breg[ct][ks], af[ks], acc[ct], 0, 0, 0);
        __builtin_amdgcn_s_setprio(0);

        // ---- stores: lane holds C[row=lr][col=w*64+ct*16+lg*4 ..+3] ----
        const size_t row0 = row00 + (size_t)t * 16;
        #pragma unroll
        for (int ct = 0; ct < 4; ++ct) {
            f32x4 o = acc[ct];
            o[0] += bv[ct].x; o[1] += bv[ct].y; o[2] += bv[ct].z; o[3] += bv[ct].w;
            *(f32x4*)(out + (row0 + lr) * 256 + w * 64 + ct * 16 + lg * 4) = o;
        }
        // MFMA(t) read Aq[t&1] before barrier(t+1); next write to Aq[t&1] is
        // quant(t+2) which is after barrier(t+1) -> max skew 1 iter, safe.
    }
}

extern "C" void kernel_launch(void* const* d_in, const int* in_sizes, int n_in,
                              void* d_out, int out_size, void* d_ws, size_t ws_size,
                              hipStream_t stream) {
    const float* x    = (const float*)d_in[0];
    const float* wk   = (const float*)d_in[1];
    const float* bias = (const float*)d_in[2];
    float* out = (float*)d_out;
    u16* Bq    = (u16*)d_ws;                  // 256*256 bf16 = 128 KB scratch
    wq_kernel<<<64, 256, 0, stream>>>(wk, Bq);
    mx_gemm<<<NBLK, 256, 0, stream>>>(x, Bq, bias, out);
}